// Round 6
// baseline (58.865 us; speedup 1.0000x reference)
//
#include <hip/hip_runtime.h>

#define NFEAT 40
#define EMB   64
#define ATT   32
#define NPAIR 780
#define NMT   49      // 49 M-tiles x 16 pairs = 784 (padded)
#define XH_S  72      // fp16 x LDS stride (elems) -> 144 B row stride

typedef __attribute__((ext_vector_type(8))) _Float16 f16x8;
typedef __attribute__((ext_vector_type(4))) _Float16 f16x4;
typedef __attribute__((ext_vector_type(4))) float    f32x4;

template <int CTRL>
__device__ __forceinline__ float dpp_add_f(float v) {
  int t = __builtin_amdgcn_update_dpp(0, __float_as_int(v), CTRL, 0xF, 0xF, true);
  return v + __int_as_float(t);
}
__device__ __forceinline__ float rowsum16(float v) {
  v = dpp_add_f<0x128>(v);
  v = dpp_add_f<0x124>(v);
  v = dpp_add_f<0x122>(v);
  v = dpp_add_f<0x121>(v);
  return v;
}

__device__ __forceinline__ int pair_off(int i) { return 39 * i - (i * (i - 1)) / 2; }

extern "C" __global__ __launch_bounds__(256, 6)
void afm_kernel(const float* __restrict__ xg, const float* __restrict__ Wg,
                const float* __restrict__ bg, const float* __restrict__ hg,
                const float* __restrict__ pg, float* __restrict__ outg, int nbatch) {
  __shared__ __align__(16) _Float16 xh[NFEAT * XH_S];   // 5760 B
  __shared__ float red[4][2];

  const int tid  = threadIdx.x;
  const int lane = tid & 63, wid = tid >> 6;
  const int l15  = lane & 15, hk = lane >> 4;

  // ---- once per block: W fragments (A operand; D = [att][pair]) ----
  f16x8 wf0[2], wf1[2], wf2[2];
#pragma unroll
  for (int kk = 0; kk < 2; kk++) {
    f16x8 r0, r1, r2;
#pragma unroll
    for (int t = 0; t < 8; t++) {
      int krow = kk * 32 + hk * 8 + t;
      r0[t] = (_Float16)Wg[krow * ATT + l15];
      r1[t] = (_Float16)Wg[krow * ATT + 16 + l15];
      _Float16 pv = (_Float16)pg[krow];
      r2[t] = (l15 == 0) ? pv : (_Float16)0.f;   // A row 0 = p vector
    }
    wf0[kk] = r0; wf1[kk] = r1; wf2[kk] = r2;
  }
  // bias/h for acc0 atts hk*4+r, acc1 atts 16+hk*4+r
  const float4 b0 = *(const float4*)&bg[hk * 4];
  const float4 b1 = *(const float4*)&bg[16 + hk * 4];
  const float4 h0 = *(const float4*)&hg[hk * 4];
  const float4 h1 = *(const float4*)&hg[16 + hk * 4];

  // ---- once per block: per-wave pair LDS byte offsets in registers ----
  unsigned pij[13];
#pragma unroll
  for (int t = 0; t < 13; t++) {
    int p = (wid + 4 * t) * 16 + l15;
    int i = 0, j = 0;
    if (p < NPAIR) {
      i = (int)((79.0f - sqrtf(6241.0f - 8.0f * (float)p)) * 0.5f);
      if (i < 0) i = 0;
      while (pair_off(i + 1) <= p) ++i;
      while (pair_off(i) > p) --i;
      j = i + 1 + (p - pair_off(i));
    }
    pij[t] = (unsigned)(i * 144 + hk * 16) | ((unsigned)(j * 144 + hk * 16) << 16);
  }

  const f32x4 kz = {0.f, 0.f, 0.f, 0.f};   // persistent zero-C block

  // ---- 2 batches per block ----
  for (int it = 0; it < 2; it++) {
    const int bb = blockIdx.x * 2 + it;
    if (bb >= nbatch) break;

    // stage x -> fp16 LDS (RNE scalar casts; compiler packs)
    const float4* xsrc = (const float4*)(xg + (size_t)bb * (NFEAT * EMB));
    for (int f = tid; f < NFEAT * EMB / 4; f += 256) {
      float4 v = xsrc[f];
      int row = f >> 4, c = (f & 15) * 4;
      f16x4 h4 = {(_Float16)v.x, (_Float16)v.y, (_Float16)v.z, (_Float16)v.w};
      *(f16x4*)&xh[row * XH_S + c] = h4;
    }
    __syncthreads();

    float sum_e = 0.f, sum_es = 0.f;
#pragma unroll
    for (int t = 0; t < 13; t++) {
      if (t < 12 || wid == 0) {               // tile m = wid + 4t < 49
        const unsigned offi = pij[t] & 0xFFFFu;
        const unsigned offj = pij[t] >> 16;
        const f16x8 xi0 = *(const f16x8*)((const char*)xh + offi);
        const f16x8 xj0 = *(const f16x8*)((const char*)xh + offj);
        const f16x8 xi1 = *(const f16x8*)((const char*)xh + offi + 64);
        const f16x8 xj1 = *(const f16x8*)((const char*)xh + offj + 64);
        f16x8 af0 = xi0 * xj0;
        f16x8 af1 = xi1 * xj1;
        f32x4 acc0 = __builtin_amdgcn_mfma_f32_16x16x32_f16(wf0[0], af0, kz, 0, 0, 0);
        f32x4 acc1 = __builtin_amdgcn_mfma_f32_16x16x32_f16(wf1[0], af0, kz, 0, 0, 0);
        f32x4 acc2 = __builtin_amdgcn_mfma_f32_16x16x32_f16(wf2[0], af0, kz, 0, 0, 0);
        acc0 = __builtin_amdgcn_mfma_f32_16x16x32_f16(wf0[1], af1, acc0, 0, 0, 0);
        acc1 = __builtin_amdgcn_mfma_f32_16x16x32_f16(wf1[1], af1, acc1, 0, 0, 0);
        acc2 = __builtin_amdgcn_mfma_f32_16x16x32_f16(wf2[1], af1, acc2, 0, 0, 0);
        // logit: 8 in-lane atts, then sum over the 4 hk groups
        float va = fmaf(fmaxf(acc0[0] + b0.x, 0.f), h0.x,
                   fmaf(fmaxf(acc0[1] + b0.y, 0.f), h0.y,
                   fmaf(fmaxf(acc0[2] + b0.z, 0.f), h0.z,
                        fmaxf(acc0[3] + b0.w, 0.f) * h0.w)));
        float vb = fmaf(fmaxf(acc1[0] + b1.x, 0.f), h1.x,
                   fmaf(fmaxf(acc1[1] + b1.y, 0.f), h1.y,
                   fmaf(fmaxf(acc1[2] + b1.z, 0.f), h1.z,
                        fmaxf(acc1[3] + b1.w, 0.f) * h1.w)));
        float v = va + vb;
        v += __shfl_xor(v, 16, 64);
        v += __shfl_xor(v, 32, 64);
        float e = __expf(v);
        if (t == 12) e = (l15 < 12) ? e : 0.f;  // pairs 780..783 are padding
        sum_e += e;                              // counted 4x (hk groups)
        sum_es = fmaf(e, acc2[0], sum_es);       // acc2[0]==0 unless hk==0
      }
    }

    // wave reduce then block reduce
    sum_e = rowsum16(sum_e);
    sum_e += __shfl_xor(sum_e, 16, 64);
    sum_e += __shfl_xor(sum_e, 32, 64);
    sum_es = rowsum16(sum_es);
    sum_es += __shfl_xor(sum_es, 16, 64);
    sum_es += __shfl_xor(sum_es, 32, 64);
    if (lane == 0) { red[wid][0] = sum_e; red[wid][1] = sum_es; }
    __syncthreads();
    if (tid == 0) {
      float Z = (red[0][0] + red[1][0] + red[2][0] + red[3][0]) * 0.25f;
      float S = red[0][1] + red[1][1] + red[2][1] + red[3][1];
      outg[bb] = S / Z;
    }
  }
}

extern "C" void kernel_launch(void* const* d_in, const int* in_sizes, int n_in,
                              void* d_out, int out_size, void* d_ws, size_t ws_size,
                              hipStream_t stream) {
  const float* xg = (const float*)d_in[0];
  const float* Wg = (const float*)d_in[1];
  const float* bg = (const float*)d_in[2];
  const float* hg = (const float*)d_in[3];
  const float* pg = (const float*)d_in[4];
  float* outg = (float*)d_out;
  const int Bn = in_sizes[0] / (NFEAT * EMB);
  const int nblk = (Bn + 1) / 2;
  afm_kernel<<<dim3(nblk), dim3(256), 0, stream>>>(xg, Wg, bg, hg, pg, outg, Bn);
}

// Round 7
// 39.819 us; speedup vs baseline: 1.4783x; 1.4783x over previous
//
#include <hip/hip_runtime.h>

#define NFEAT 40
#define EMB   64
#define ATT   32
#define NPAIR 780
#define NMT   49      // 49 M-tiles x 16 pairs = 784 (padded)
#define XH_S  72      // fp16 x LDS stride (elems) -> 144 B row stride

typedef __attribute__((ext_vector_type(8))) _Float16 f16x8;
typedef __attribute__((ext_vector_type(4))) _Float16 f16x4;
typedef __attribute__((ext_vector_type(4))) float    f32x4;

template <int CTRL>
__device__ __forceinline__ float dpp_add_f(float v) {
  int t = __builtin_amdgcn_update_dpp(0, __float_as_int(v), CTRL, 0xF, 0xF, true);
  return v + __int_as_float(t);
}
__device__ __forceinline__ float rowsum16(float v) {
  v = dpp_add_f<0x128>(v);
  v = dpp_add_f<0x124>(v);
  v = dpp_add_f<0x122>(v);
  v = dpp_add_f<0x121>(v);
  return v;
}

__device__ __forceinline__ int pair_off(int i) { return 39 * i - (i * (i - 1)) / 2; }

extern "C" __global__ __launch_bounds__(256)
void afm_kernel(const float* __restrict__ xg, const float* __restrict__ Wg,
                const float* __restrict__ bg, const float* __restrict__ hg,
                const float* __restrict__ pg, float* __restrict__ outg, int nbatch) {
  __shared__ __align__(16) _Float16 xh[NFEAT * XH_S];   // 5760 B
  __shared__ float red[4][2];

  const int tid  = threadIdx.x;
  const int lane = tid & 63, wid = tid >> 6;
  const int l15  = lane & 15, hk = lane >> 4;

  // ---- once per block: W fragments (A operand; D = [att][pair]) ----
  f16x8 wf0[2], wf1[2], wf2[2];
#pragma unroll
  for (int kk = 0; kk < 2; kk++) {
    f16x8 r0, r1, r2;
#pragma unroll
    for (int t = 0; t < 8; t++) {
      int krow = kk * 32 + hk * 8 + t;
      r0[t] = (_Float16)Wg[krow * ATT + l15];
      r1[t] = (_Float16)Wg[krow * ATT + 16 + l15];
      _Float16 pv = (_Float16)pg[krow];
      r2[t] = (l15 == 0) ? pv : (_Float16)0.f;   // A row 0 = p vector
    }
    wf0[kk] = r0; wf1[kk] = r1; wf2[kk] = r2;
  }
  // bias/h for acc0 atts hk*4+r, acc1 atts 16+hk*4+r
  const float4 b0 = *(const float4*)&bg[hk * 4];
  const float4 b1 = *(const float4*)&bg[16 + hk * 4];
  const float4 h0 = *(const float4*)&hg[hk * 4];
  const float4 h1 = *(const float4*)&hg[16 + hk * 4];

  // ---- once per block: per-wave pair LDS byte offsets in registers ----
  unsigned pij[13];
#pragma unroll
  for (int t = 0; t < 13; t++) {
    int p = (wid + 4 * t) * 16 + l15;
    int i = 0, j = 0;
    if (p < NPAIR) {
      i = (int)((79.0f - sqrtf(6241.0f - 8.0f * (float)p)) * 0.5f);
      if (i < 0) i = 0;
      while (pair_off(i + 1) <= p) ++i;
      while (pair_off(i) > p) --i;
      j = i + 1 + (p - pair_off(i));
    }
    pij[t] = (unsigned)(i * 144 + hk * 16) | ((unsigned)(j * 144 + hk * 16) << 16);
  }

  const f32x4 kz = {0.f, 0.f, 0.f, 0.f};   // persistent zero-C block

  // ---- 2 batches per block ----
  for (int it = 0; it < 2; it++) {
    const int bb = blockIdx.x * 2 + it;
    if (bb >= nbatch) break;

    // stage x -> fp16 LDS (RNE scalar casts; compiler packs)
    const float4* xsrc = (const float4*)(xg + (size_t)bb * (NFEAT * EMB));
    for (int f = tid; f < NFEAT * EMB / 4; f += 256) {
      float4 v = xsrc[f];
      int row = f >> 4, c = (f & 15) * 4;
      f16x4 h4 = {(_Float16)v.x, (_Float16)v.y, (_Float16)v.z, (_Float16)v.w};
      *(f16x4*)&xh[row * XH_S + c] = h4;
    }
    __syncthreads();

    float sum_e = 0.f, sum_es = 0.f;
#pragma unroll
    for (int t = 0; t < 13; t++) {
      if (t < 12 || wid == 0) {               // tile m = wid + 4t < 49
        const unsigned offi = pij[t] & 0xFFFFu;
        const unsigned offj = pij[t] >> 16;
        const f16x8 xi0 = *(const f16x8*)((const char*)xh + offi);
        const f16x8 xj0 = *(const f16x8*)((const char*)xh + offj);
        const f16x8 xi1 = *(const f16x8*)((const char*)xh + offi + 64);
        const f16x8 xj1 = *(const f16x8*)((const char*)xh + offj + 64);
        f16x8 af0 = xi0 * xj0;
        f16x8 af1 = xi1 * xj1;
        f32x4 acc0 = __builtin_amdgcn_mfma_f32_16x16x32_f16(wf0[0], af0, kz, 0, 0, 0);
        f32x4 acc1 = __builtin_amdgcn_mfma_f32_16x16x32_f16(wf1[0], af0, kz, 0, 0, 0);
        f32x4 acc2 = __builtin_amdgcn_mfma_f32_16x16x32_f16(wf2[0], af0, kz, 0, 0, 0);
        acc0 = __builtin_amdgcn_mfma_f32_16x16x32_f16(wf0[1], af1, acc0, 0, 0, 0);
        acc1 = __builtin_amdgcn_mfma_f32_16x16x32_f16(wf1[1], af1, acc1, 0, 0, 0);
        acc2 = __builtin_amdgcn_mfma_f32_16x16x32_f16(wf2[1], af1, acc2, 0, 0, 0);
        // logit: 8 in-lane atts, then sum over the 4 hk groups
        float va = fmaf(fmaxf(acc0[0] + b0.x, 0.f), h0.x,
                   fmaf(fmaxf(acc0[1] + b0.y, 0.f), h0.y,
                   fmaf(fmaxf(acc0[2] + b0.z, 0.f), h0.z,
                        fmaxf(acc0[3] + b0.w, 0.f) * h0.w)));
        float vb = fmaf(fmaxf(acc1[0] + b1.x, 0.f), h1.x,
                   fmaf(fmaxf(acc1[1] + b1.y, 0.f), h1.y,
                   fmaf(fmaxf(acc1[2] + b1.z, 0.f), h1.z,
                        fmaxf(acc1[3] + b1.w, 0.f) * h1.w)));
        float v = va + vb;
        v += __shfl_xor(v, 16, 64);
        v += __shfl_xor(v, 32, 64);
        float e = __expf(v);
        if (t == 12) e = (l15 < 12) ? e : 0.f;  // pairs 780..783 are padding
        sum_e += e;                              // counted 4x (hk groups)
        sum_es = fmaf(e, acc2[0], sum_es);       // acc2[0]==0 unless hk==0
      }
    }

    // wave reduce then block reduce
    sum_e = rowsum16(sum_e);
    sum_e += __shfl_xor(sum_e, 16, 64);
    sum_e += __shfl_xor(sum_e, 32, 64);
    sum_es = rowsum16(sum_es);
    sum_es += __shfl_xor(sum_es, 16, 64);
    sum_es += __shfl_xor(sum_es, 32, 64);
    if (lane == 0) { red[wid][0] = sum_e; red[wid][1] = sum_es; }
    __syncthreads();
    if (tid == 0) {
      float Z = (red[0][0] + red[1][0] + red[2][0] + red[3][0]) * 0.25f;
      float S = red[0][1] + red[1][1] + red[2][1] + red[3][1];
      outg[bb] = S / Z;
    }
  }
}

extern "C" void kernel_launch(void* const* d_in, const int* in_sizes, int n_in,
                              void* d_out, int out_size, void* d_ws, size_t ws_size,
                              hipStream_t stream) {
  const float* xg = (const float*)d_in[0];
  const float* Wg = (const float*)d_in[1];
  const float* bg = (const float*)d_in[2];
  const float* hg = (const float*)d_in[3];
  const float* pg = (const float*)d_in[4];
  float* outg = (float*)d_out;
  const int Bn = in_sizes[0] / (NFEAT * EMB);
  const int nblk = (Bn + 1) / 2;
  afm_kernel<<<dim3(nblk), dim3(256), 0, stream>>>(xg, Wg, bg, hg, pg, outg, Bn);
}